// Round 14
// baseline (718.698 us; speedup 1.0000x reference)
//
#include <hip/hip_runtime.h>
#include <hip/hip_bf16.h>
#include <stdint.h>

#define TOK 4096   // B*S
#define HD  1024   // H
#define NE  8      // experts
#define ID  2688   // I
#define MAXK 6
#define AHID 50
#define NROW 58    // NE + AHID
#define KCH 64     // logits split-K chunk
#define NCH (HD / KCH)  // 16

#define BM 128
#define BN 128
#define BK 64
#define NTM (TOK / BM)          // 32
#define NID2 (2 * ID)           // 5376 combined gate|up cols
#define NTN_GUC (NID2 / BN)     // 42
#define NB_GUC (NTN_GUC * NTM)  // 1344
#define CVTB 384                // fused down-w cvt blocks in gateupC (z=0)
#define NB_D 256                // down item space per expert: 8 tn x 32 tm
#define PD_BLOCKS 768           // persistent down blocks (3/CU x 256)
#define CVTGU 1024              // gu-cvt blocks appended to logits dispatch

typedef float  f32x4  __attribute__((ext_vector_type(4)));
typedef __bf16 bf16x8 __attribute__((ext_vector_type(8)));
typedef ushort ushort8v __attribute__((ext_vector_type(8)));

__device__ __forceinline__ ushort f2bf(float f) {
  union { float f; uint32_t u; } v; v.f = f;
  return (ushort)((v.u + 0x7FFFu + ((v.u >> 16) & 1u)) >> 16);  // RNE
}
__device__ __forceinline__ float bf2f(ushort u) {
  union { uint32_t u; float f; } v; v.u = (uint32_t)u << 16; return v.f;
}

// global -> LDS direct load, 16B per lane. LDS dest must be wave-uniform.
#define GLD_LDS16(gp, lp)                                                      \
  __builtin_amdgcn_global_load_lds(                                            \
      (const __attribute__((address_space(1))) uint32_t*)(uintptr_t)(gp),      \
      (__attribute__((address_space(3))) uint32_t*)(uint32_t)(uintptr_t)(lp),  \
      16, 0, 0)

// ---------------- fp32 -> bf16 convert (fallback path only) ----------------
__global__ void k_cvt(const float* __restrict__ src, ushort* __restrict__ dst, int n) {
  int idx = blockIdx.x * blockDim.x + threadIdx.x;
  int stride = gridDim.x * blockDim.x;
  for (int i = idx * 8; i < n; i += stride * 8) {
    float4 a = *(const float4*)(src + i);
    float4 b = *(const float4*)(src + i + 4);
    ushort8v o;
    o[0] = f2bf(a.x); o[1] = f2bf(a.y); o[2] = f2bf(a.z); o[3] = f2bf(a.w);
    o[4] = f2bf(b.x); o[5] = f2bf(b.y); o[6] = f2bf(b.z); o[7] = f2bf(b.w);
    *(ushort8v*)(dst + i) = o;
  }
}

// ------- merged logits (blocks 0..255) + gate|up bf16 build (256..1279) -----
// logits: split-K chunk c = bid>>4, token block t0 = (bid&15)*256; LDS-staged
// x (emits bf16 Xb), wave-uniform W rows -> SGPR FMA. cvt part: builds
// Wgu[e][q][h], q=p*128+r; r<64 gate row p*64+r else up row p*64+r-64.
__global__ __launch_bounds__(256) void k_logitsF(
    const float* __restrict__ x, const float* __restrict__ rw,
    const float* __restrict__ aw1, float* __restrict__ partial,
    ushort* __restrict__ Xb,
    const float* __restrict__ g, const float* __restrict__ u,
    ushort* __restrict__ Wgu) {
  const int bid = blockIdx.x;
  const int tid = threadIdx.x;
  if (bid >= 256) {                            // gate|up cvt blocks
    const int cb = bid - 256;
    const int total = NE * NID2 * (HD / 8);
    const int stride = CVTGU * 256;
    for (int i8 = cb * 256 + tid; i8 < total; i8 += stride) {
      const int col = (i8 & (HD / 8 - 1)) * 8;
      const int row = i8 >> 7;
      const int e = row / NID2;
      const int q = row - e * NID2;
      const int p = q >> 7, r = q & 127;
      const float* src = ((r < 64) ? g + ((size_t)e * ID + p * 64 + r) * HD
                                   : u + ((size_t)e * ID + p * 64 + (r - 64)) * HD) + col;
      float4 a = *(const float4*)(src);
      float4 b = *(const float4*)(src + 4);
      ushort8v o;
      o[0] = f2bf(a.x); o[1] = f2bf(a.y); o[2] = f2bf(a.z); o[3] = f2bf(a.w);
      o[4] = f2bf(b.x); o[5] = f2bf(b.y); o[6] = f2bf(b.z); o[7] = f2bf(b.w);
      *(ushort8v*)(Wgu + (size_t)row * HD + col) = o;
    }
    return;
  }
  __shared__ float xs[256][KCH + 1];
  const int c = bid >> 4;
  const int t0 = (bid & 15) * 256;
  const int k0 = c * KCH;
#pragma unroll
  for (int j = 0; j < 16; ++j) {
    const int id4 = j * 256 + tid;
    const int row = id4 >> 4;
    const int c4 = (id4 & 15) * 4;
    float4 v = *(const float4*)(x + (size_t)(t0 + row) * HD + k0 + c4);
    xs[row][c4 + 0] = v.x; xs[row][c4 + 1] = v.y;
    xs[row][c4 + 2] = v.z; xs[row][c4 + 3] = v.w;
    ushort4 o; o.x = f2bf(v.x); o.y = f2bf(v.y); o.z = f2bf(v.z); o.w = f2bf(v.w);
    *(ushort4*)(Xb + (size_t)(t0 + row) * HD + k0 + c4) = o;
  }
  __syncthreads();
  float acc[NROW];
#pragma unroll
  for (int r = 0; r < NROW; ++r) acc[r] = 0.f;
  for (int k4 = 0; k4 < KCH; k4 += 4) {
    const float x0 = xs[tid][k4 + 0], x1 = xs[tid][k4 + 1];
    const float x2 = xs[tid][k4 + 2], x3 = xs[tid][k4 + 3];
#pragma unroll
    for (int r = 0; r < NROW; ++r) {
      const float* wp = ((r < NE) ? (rw + (size_t)r * HD)
                                  : (aw1 + (size_t)(r - NE) * HD)) + k0 + k4;
      acc[r] += x0 * wp[0] + x1 * wp[1] + x2 * wp[2] + x3 * wp[3];
    }
  }
  const int t = t0 + tid;
#pragma unroll
  for (int r = 0; r < NROW; ++r)
    partial[((size_t)c * NROW + r) * TOK + t] = acc[r];
}

// -------- merged chunk-reduce + softmax/actor/top-k/expert lists ------------
__global__ __launch_bounds__(64) void k_select2(
    const float* __restrict__ partial, const float* __restrict__ ab1_,
    const float* __restrict__ aw2_, const float* __restrict__ ab2_,
    float* __restrict__ scores, int* __restrict__ idx, int* __restrict__ cnt) {
  const int lane = threadIdx.x;
  const int t = blockIdx.x * 64 + lane;
  float d[NROW];
#pragma unroll
  for (int r = 0; r < NROW; ++r) {
    float s = 0.f;
#pragma unroll
    for (int c = 0; c < NCH; ++c)
      s += partial[((size_t)c * NROW + r) * TOK + t];
    d[r] = s;
  }
  float m = d[0];
#pragma unroll
  for (int e = 1; e < NE; ++e) m = fmaxf(m, d[e]);
  float p[NE]; float sum = 0.f;
#pragma unroll
  for (int e = 0; e < NE; ++e) { p[e] = expf(d[e] - m); sum += p[e]; }
  float inv = 1.f / sum;
#pragma unroll
  for (int e = 0; e < NE; ++e) p[e] *= inv;
  float lg[MAXK];
#pragma unroll
  for (int k = 0; k < MAXK; ++k) lg[k] = ab2_[k];
#pragma unroll
  for (int i = 0; i < AHID; ++i) {
    float v = d[NE + i] + ab1_[i];
    float gg = 0.5f * v * (1.f + tanhf(0.7978845608028654f * (v + 0.044715f * v * v * v)));
#pragma unroll
    for (int k = 0; k < MAXK; ++k) lg[k] += gg * aw2_[k * AHID + i];
  }
  int best = 0; float bv = fminf(fmaxf(lg[0], -30.f), 30.f);
#pragma unroll
  for (int k = 1; k < MAXK; ++k) {
    float lv = fminf(fmaxf(lg[k], -30.f), 30.f);
    if (lv > bv) { bv = lv; best = k; }
  }
  const int kk = best + 1;
  float sc[NE];
#pragma unroll
  for (int e = 0; e < NE; ++e) {
    int rank = 0;
#pragma unroll
    for (int j = 0; j < NE; ++j)
      rank += (p[j] > p[e]) || (p[j] == p[e] && j < e);
    sc[e] = (rank < kk) ? p[e] : 0.f;
    scores[(size_t)t * NE + e] = sc[e];
  }
#pragma unroll
  for (int e = 0; e < NE; ++e) {
    unsigned long long msk = __ballot(sc[e] > 0.f);
    int npop = __popcll(msk);
    int mypos = __popcll(msk & ((1ull << lane) - 1ull));
    int base = 0;
    if (lane == 0 && npop) base = atomicAdd(cnt + e, npop);
    base = __shfl(base, 0);
    if (sc[e] > 0.f) idx[e * TOK + base + mypos] = t;
  }
}

// ---------------- combined gate|up GEMM + silu exchange (r11-proven) --------
__global__ __launch_bounds__(256, 2) void k_gateupC(
    const ushort* __restrict__ X, const int* __restrict__ idx,
    const int* __restrict__ cnt, const ushort* __restrict__ Wc,
    ushort* __restrict__ act, const int e0, const int actStrideRows,
    const float* __restrict__ dwsrc, ushort* __restrict__ dwdst) {
  __shared__ __attribute__((aligned(16))) ushort lds[BM * BK + BN * BK];  // 32KB
  ushort* As = lds;
  ushort* Bs = lds + BM * BK;

  const int bid = blockIdx.x;
  if (bid >= NB_GUC) {                                  // fused down-w cvt
    if (blockIdx.z != 0) return;
    const int cb = bid - NB_GUC;
    const int ncvt = NE * HD * ID;
    const int stride = CVTB * 256 * 8;
    for (int i = (cb * 256 + (int)threadIdx.x) * 8; i < ncvt; i += stride) {
      float4 a = *(const float4*)(dwsrc + i);
      float4 b = *(const float4*)(dwsrc + i + 4);
      ushort8v o;
      o[0] = f2bf(a.x); o[1] = f2bf(a.y); o[2] = f2bf(a.z); o[3] = f2bf(a.w);
      o[4] = f2bf(b.x); o[5] = f2bf(b.y); o[6] = f2bf(b.z); o[7] = f2bf(b.w);
      *(ushort8v*)(dwdst + i) = o;
    }
    return;
  }

  const int e = e0 + blockIdx.z;
  const int n = cnt[e];
  const int logical = (bid & 7) * (NB_GUC / 8) + (bid >> 3);
  const int tn = logical >> 5;
  const int tm = logical & (NTM - 1);
  const int row0 = tm * BM;
  if (row0 >= n) return;
  const int* idx_e = idx + e * TOK;
  const ushort* WcE = Wc + (size_t)e * NID2 * HD;
  ushort* actE = act + (size_t)actStrideRows * e * ID;

  const int tid = threadIdx.x;
  const int lane = tid & 63;
  const int w = tid >> 6;
  const int wr = (w >> 1) * 64;
  const int wc = (w & 1) * 64;
  const int srow = lane >> 3;
  const int scol = ((lane & 7) ^ srow) * 8;       // T2: inverse-swz source
  const int col0 = tn * BN;

  f32x4 acc[4][4] = {};

  const ushort* pa[4]; const ushort* pb[4];
  ushort* la[4]; ushort* lb[4];
#pragma unroll
  for (int j = 0; j < 4; ++j) {
    const int cc = w * 4 + j;
    const int r = cc * 8 + srow;
    const int token = idx_e[min(row0 + r, n - 1)];
    pa[j] = X   + (size_t)token * HD + scol;
    pb[j] = WcE + (size_t)(col0 + r) * HD + scol;
    la[j] = &As[cc * 512]; lb[j] = &Bs[cc * 512];
  }

  for (int kt = 0; kt < HD / BK; ++kt) {
    const int k0 = kt * BK;
    __syncthreads();
#pragma unroll
    for (int j = 0; j < 4; ++j) {
      GLD_LDS16(pa[j] + k0, la[j]);
      GLD_LDS16(pb[j] + k0, lb[j]);
    }
    __syncthreads();
#pragma unroll
    for (int kk = 0; kk < 2; ++kk) {
      const int kc = kk * 32 + (lane >> 4) * 8;
      const int rr = lane & 15;
      const int kcs = (((kc >> 3) ^ (rr & 7)) << 3);   // T2: swizzled read
      bf16x8 af[4], bf_[4];
#pragma unroll
      for (int m = 0; m < 4; ++m)
        af[m] = *(const bf16x8*)&As[(wr + m * 16 + rr) * BK + kcs];
#pragma unroll
      for (int nn = 0; nn < 4; ++nn)
        bf_[nn] = *(const bf16x8*)&Bs[(wc + nn * 16 + rr) * BK + kcs];
#pragma unroll
      for (int m = 0; m < 4; ++m)
#pragma unroll
        for (int nn = 0; nn < 4; ++nn)
          acc[m][nn] = __builtin_amdgcn_mfma_f32_16x16x32_bf16(af[m], bf_[nn], acc[m][nn], 0, 0, 0);
    }
  }

  const int erow = (lane >> 4) * 4, ecol = lane & 15;
  float* exch = (float*)lds;
  __syncthreads();
  if (w & 1) {                                // u-waves
#pragma unroll
    for (int m = 0; m < 4; ++m) {
      const int rbase = wr + m * 16 + erow;
#pragma unroll
      for (int nn = 0; nn < 4; ++nn) {
        const int c = nn * 16 + ecol;
#pragma unroll
        for (int j = 0; j < 4; ++j)
          exch[(rbase + j) * 64 + c] = acc[m][nn][j];
      }
    }
  }
  __syncthreads();
  if (!(w & 1)) {                             // g-waves
#pragma unroll
    for (int m = 0; m < 4; ++m) {
      const int rbase = wr + m * 16 + erow;
#pragma unroll
      for (int nn = 0; nn < 4; ++nn) {
        const int c = nn * 16 + ecol;
        const int gc = tn * 64 + c;
#pragma unroll
        for (int j = 0; j < 4; ++j) {
          float g = acc[m][nn][j];
          float u = exch[(rbase + j) * 64 + c];
          float h = (g / (1.f + __expf(-g))) * u;
          actE[(size_t)(row0 + rbase + j) * ID + gc] = f2bf(h);
        }
      }
    }
  }
}

// ------- persistent grouped down GEMM (r11 body, grid-stride items) ---------
// ~960 active items on a 768-block persistent grid kills the 25%-idle tail
// round of the 2048-block dispatch (blocks/CU = 3 measured).
__global__ __launch_bounds__(256, 2) void k_downP(
    const ushort* __restrict__ act, const ushort* __restrict__ Wd,
    const int* __restrict__ idx, const int* __restrict__ cnt,
    ushort* __restrict__ y) {
  __shared__ __attribute__((aligned(16))) ushort As[BM * BK];
  __shared__ __attribute__((aligned(16))) ushort Bs[BN * BK];

  const int tid = threadIdx.x;
  const int lane = tid & 63;
  const int w = tid >> 6;
  const int wr = (w >> 1) * 64;
  const int wc = (w & 1) * 64;
  const int srow = lane >> 3;
  const int scol = ((lane & 7) ^ srow) * 8;       // T2: inverse-swz source
  const int erow = (lane >> 4) * 4, ecol = lane & 15;

  for (int item = blockIdx.x; item < NE * NB_D; item += PD_BLOCKS) {
    const int e = item >> 8;                      // NB_D = 256
    const int bid = item & (NB_D - 1);
    const int logical = (bid & 7) * (NB_D / 8) + (bid >> 3);
    const int tn = logical >> 5;
    const int tm = logical & (NTM - 1);
    const int n = cnt[e];
    const int row0 = tm * BM;
    if (row0 >= n) continue;
    const int* idx_e = idx + e * TOK;
    const ushort* A = act + (size_t)e * TOK * ID;
    const ushort* W = Wd + (size_t)e * HD * ID;
    ushort* yE = y + (size_t)e * TOK * HD;
    const int col0 = tn * BN;

    f32x4 acc[4][4] = {};

    const ushort* pa[4]; const ushort* pb[4];
    ushort* la[4]; ushort* lb[4];
#pragma unroll
    for (int j = 0; j < 4; ++j) {
      const int cc = w * 4 + j;
      const int r = cc * 8 + srow;
      pa[j] = A + (size_t)min(row0 + r, n - 1) * ID + scol;
      pb[j] = W + (size_t)(col0 + r) * ID + scol;
      la[j] = &As[cc * 512]; lb[j] = &Bs[cc * 512];
    }

    for (int kt = 0; kt < ID / BK; ++kt) {
      const int k0 = kt * BK;
      __syncthreads();
#pragma unroll
      for (int j = 0; j < 4; ++j) {
        GLD_LDS16(pa[j] + k0, la[j]);
        GLD_LDS16(pb[j] + k0, lb[j]);
      }
      __syncthreads();
#pragma unroll
      for (int kk = 0; kk < 2; ++kk) {
        const int kc = kk * 32 + (lane >> 4) * 8;
        const int rr = lane & 15;
        const int kcs = (((kc >> 3) ^ (rr & 7)) << 3);
        bf16x8 af[4], bf_[4];
#pragma unroll
        for (int m = 0; m < 4; ++m)
          af[m] = *(const bf16x8*)&As[(wr + m * 16 + rr) * BK + kcs];
#pragma unroll
        for (int nn = 0; nn < 4; ++nn)
          bf_[nn] = *(const bf16x8*)&Bs[(wc + nn * 16 + rr) * BK + kcs];
#pragma unroll
        for (int m = 0; m < 4; ++m)
#pragma unroll
          for (int nn = 0; nn < 4; ++nn)
            acc[m][nn] = __builtin_amdgcn_mfma_f32_16x16x32_bf16(af[m], bf_[nn], acc[m][nn], 0, 0, 0);
      }
    }

#pragma unroll
    for (int m = 0; m < 4; ++m) {
      const int cr0 = row0 + wr + m * 16 + erow;
#pragma unroll
      for (int j = 0; j < 4; ++j) {
        const int cr = cr0 + j;
        if (cr < n) {
          const int token = idx_e[cr];
          ushort* yp = yE + (size_t)token * HD + col0 + wc;
#pragma unroll
          for (int nn = 0; nn < 4; ++nn)
            yp[nn * 16 + ecol] = f2bf(acc[m][nn][j]);
        }
      }
    }
  }
}

// ---------------- combine: out[t] = sum_e score[t][e] * y[e][t] -------------
__global__ __launch_bounds__(256) void k_combine(
    const ushort* __restrict__ y, const float* __restrict__ scores,
    float* __restrict__ out) {
  const int w = threadIdx.x >> 6, lane = threadIdx.x & 63;
  const int t = blockIdx.x * 4 + w;
  const int c0 = lane * 16;
  float acc[16];
#pragma unroll
  for (int i = 0; i < 16; ++i) acc[i] = 0.f;
  const float* sc = scores + (size_t)t * NE;
#pragma unroll
  for (int e = 0; e < NE; ++e) {
    const float s = sc[e];
    if (s > 0.f) {
      const ushort8v* yp = (const ushort8v*)(y + ((size_t)e * TOK + t) * HD + c0);
      ushort8v v0 = yp[0], v1 = yp[1];
#pragma unroll
      for (int i = 0; i < 8; ++i) acc[i] += s * bf2f(v0[i]);
#pragma unroll
      for (int i = 0; i < 8; ++i) acc[8 + i] += s * bf2f(v1[i]);
    }
  }
  float* op = out + (size_t)t * HD + c0;
#pragma unroll
  for (int i = 0; i < 4; ++i)
    *(float4*)(op + 4 * i) = make_float4(acc[4*i], acc[4*i+1], acc[4*i+2], acc[4*i+3]);
}

// ---------------- fallback down (per-expert, accumulate into out) -----------
__global__ __launch_bounds__(256) void k_down64(
    const ushort* __restrict__ act, const ushort* __restrict__ Wd,
    const float* __restrict__ scores, const int* __restrict__ idx,
    const int* __restrict__ cnt, const int e, float* __restrict__ out) {
  __shared__ __attribute__((aligned(16))) ushort As[64 * 64];
  __shared__ __attribute__((aligned(16))) ushort Bs[64 * 64];
  const int n = cnt[e];
  const int row0 = blockIdx.y * 64;
  if (row0 >= n) return;
  const int* idx_e = idx + e * TOK;
  const ushort* A = act;
  const ushort* W = Wd + (size_t)e * HD * ID;
  const int col0 = blockIdx.x * 64;
  const int tid = threadIdx.x, lane = tid & 63, w = tid >> 6;
  const int wr = (w >> 1) * 32, wc = (w & 1) * 32;
  const int srow = lane >> 3, scol = (lane & 7) * 8;
  f32x4 acc[2][2] = {};
  const ushort* pa[2]; const ushort* pb[2];
  ushort* la[2]; ushort* lb[2];
#pragma unroll
  for (int j = 0; j < 2; ++j) {
    const int cc = w * 2 + j;
    const int r = cc * 8 + srow;
    pa[j] = A + (size_t)min(row0 + r, n - 1) * ID + scol;
    pb[j] = W + (size_t)(col0 + r) * ID + scol;
    la[j] = &As[cc * 512]; lb[j] = &Bs[cc * 512];
  }
  for (int kt = 0; kt < ID / 64; ++kt) {
    const int k0 = kt * 64;
    __syncthreads();
#pragma unroll
    for (int j = 0; j < 2; ++j) { GLD_LDS16(pa[j] + k0, la[j]); GLD_LDS16(pb[j] + k0, lb[j]); }
    __syncthreads();
#pragma unroll
    for (int kk = 0; kk < 2; ++kk) {
      const int kc = kk * 32 + (lane >> 4) * 8;
      const int rr = lane & 15;
      bf16x8 af[2], bf_[2];
#pragma unroll
      for (int m = 0; m < 2; ++m) af[m] = *(const bf16x8*)&As[(wr + m * 16 + rr) * 64 + kc];
#pragma unroll
      for (int nn = 0; nn < 2; ++nn) bf_[nn] = *(const bf16x8*)&Bs[(wc + nn * 16 + rr) * 64 + kc];
#pragma unroll
      for (int m = 0; m < 2; ++m)
#pragma unroll
        for (int nn = 0; nn < 2; ++nn)
          acc[m][nn] = __builtin_amdgcn_mfma_f32_16x16x32_bf16(af[m], bf_[nn], acc[m][nn], 0, 0, 0);
    }
  }
  const int erow = (lane >> 4) * 4, ecol = lane & 15;
#pragma unroll
  for (int m = 0; m < 2; ++m) {
    const int cr0 = row0 + wr + m * 16 + erow;
#pragma unroll
    for (int j = 0; j < 4; ++j) {
      const int cr = cr0 + j;
      if (cr < n) {
        const int token = idx_e[cr];
        const float s = scores[(size_t)token * NE + e];
        float* op = out + (size_t)token * HD + col0 + wc;
#pragma unroll
        for (int nn = 0; nn < 2; ++nn) op[nn * 16 + ecol] += s * acc[m][nn][j];
      }
    }
  }
}

extern "C" void kernel_launch(void* const* d_in, const int* in_sizes, int n_in,
                              void* d_out, int out_size, void* d_ws, size_t ws_size,
                              hipStream_t stream) {
  const float* hs       = (const float*)d_in[0];
  const float* router_w = (const float*)d_in[1];
  const float* actor_w1 = (const float*)d_in[2];
  const float* actor_b1 = (const float*)d_in[3];
  const float* actor_w2 = (const float*)d_in[4];
  const float* actor_b2 = (const float*)d_in[5];
  const float* gate_w   = (const float*)d_in[6];
  const float* up_w     = (const float*)d_in[7];
  const float* down_w   = (const float*)d_in[8];
  float* out = (float*)d_out;

  const size_t sz_x    = (size_t)TOK * HD * 2;              // 8 MB
  const size_t sz_w    = (size_t)NE * ID * HD * 2;          // 44 MB
  const size_t sz_wgu  = 2 * sz_w;                          // 88 MB combined
  const size_t sz_act1 = (size_t)TOK * ID * 2;              // 22 MB (fallback)
  const size_t sz_actC = (size_t)NE * TOK * ID * 2;         // 176 MB
  const size_t sz_part = (size_t)NCH * NROW * TOK * 4;      // 15.2 MB (aliases act)
  const size_t sz_dt   = (size_t)NROW * TOK * 4;
  const size_t sz_sc   = (size_t)TOK * NE * 4;
  const size_t sz_ix   = (size_t)NE * TOK * 4;

  const size_t fixed = sz_x + sz_wgu + sz_w;                // 140 MB
  const size_t tail  = sz_dt + sz_sc + sz_ix + 256;
  const size_t fb_act = (sz_act1 > sz_part ? sz_act1 : sz_part);
  const size_t need_fb = fixed + fb_act + tail;
  const size_t need_cb = fixed + sz_actC + tail;
  if (ws_size < need_fb) return;
  const bool combined = (ws_size >= need_cb);
  const size_t act_sz = combined ? sz_actC : fb_act;

  char* ws = (char*)d_ws;
  ushort* Xb  = (ushort*)ws;
  ushort* Wgu = (ushort*)(ws + sz_x);
  ushort* Wdb = (ushort*)(ws + sz_x + sz_wgu);
  ushort* yb  = Wgu;                                        // alias (Wgu dead after gateup)
  ushort* act = (ushort*)(ws + fixed);
  float*  partial = (float*)(ws + fixed);                   // aliases act
  float*  scores = (float*)(ws + fixed + act_sz + sz_dt);
  int*    idx    = (int*)  (ws + fixed + act_sz + sz_dt + sz_sc);
  int*    cnt    = (int*)  (ws + fixed + act_sz + sz_dt + sz_sc + sz_ix);

  hipMemsetAsync(cnt, 0, NE * 4, stream);

  // logits + gate|up cvt in one dispatch (independent work packed together)
  k_logitsF<<<256 + CVTGU, 256, 0, stream>>>(hs, router_w, actor_w1, partial, Xb,
                                             gate_w, up_w, Wgu);
  k_select2<<<TOK / 64, 64, 0, stream>>>(partial, actor_b1, actor_w2, actor_b2,
                                         scores, idx, cnt);

  if (combined) {
    k_gateupC<<<dim3(NB_GUC + CVTB, 1, NE), 256, 0, stream>>>(
        Xb, idx, cnt, Wgu, act, 0, TOK, down_w, Wdb);
    k_downP<<<PD_BLOCKS, 256, 0, stream>>>(act, Wdb, idx, cnt, yb);
    k_combine<<<TOK / 4, 256, 0, stream>>>(yb, scores, out);
  } else {
    hipMemsetAsync(out, 0, (size_t)TOK * HD * 4, stream);
    k_cvt<<<2048, 256, 0, stream>>>(down_w, Wdb, NE * ID * HD);
    for (int e = 0; e < NE; ++e) {
      k_gateupC<<<dim3(NB_GUC, 1, 1), 256, 0, stream>>>(
          Xb, idx, cnt, Wgu, act, e, 0, nullptr, nullptr);
      k_down64<<<dim3(HD / 64, TOK / 64), 256, 0, stream>>>(
          act, Wdb, scores, idx, cnt, e, out);
    }
  }
}

// Round 15
// 491.886 us; speedup vs baseline: 1.4611x; 1.4611x over previous
//
#include <hip/hip_runtime.h>
#include <hip/hip_bf16.h>
#include <stdint.h>

#define TOK 4096   // B*S
#define HD  1024   // H
#define NE  8      // experts
#define ID  2688   // I
#define MAXK 6
#define AHID 50
#define NROW 58    // NE + AHID
#define KCH 64     // logits split-K chunk
#define NCH (HD / KCH)  // 16

#define BM 128
#define BN 128
#define BK 64
#define NTM (TOK / BM)          // 32
#define NID2 (2 * ID)           // 5376 combined gate|up cols
#define NTN_GUC (NID2 / BN)     // 42
#define NB_GUC (NTN_GUC * NTM)  // 1344
#define CVTB 384                // fused down-w cvt blocks in gateupC (z=0)
#define NB_D 256                // down item space per expert: 8 tn x 32 tm
#define PD_BLOCKS 768           // persistent down blocks (3/CU x 256)
#define CVTGU 1024              // gu-cvt blocks appended to logits dispatch

typedef float  f32x4  __attribute__((ext_vector_type(4)));
typedef __bf16 bf16x8 __attribute__((ext_vector_type(8)));
typedef ushort ushort8v __attribute__((ext_vector_type(8)));

__device__ __forceinline__ ushort f2bf(float f) {
  union { float f; uint32_t u; } v; v.f = f;
  return (ushort)((v.u + 0x7FFFu + ((v.u >> 16) & 1u)) >> 16);  // RNE
}
__device__ __forceinline__ float bf2f(ushort u) {
  union { uint32_t u; float f; } v; v.u = (uint32_t)u << 16; return v.f;
}

// global -> LDS direct load, 16B per lane. LDS dest must be wave-uniform.
#define GLD_LDS16(gp, lp)                                                      \
  __builtin_amdgcn_global_load_lds(                                            \
      (const __attribute__((address_space(1))) uint32_t*)(uintptr_t)(gp),      \
      (__attribute__((address_space(3))) uint32_t*)(uint32_t)(uintptr_t)(lp),  \
      16, 0, 0)

// ---------------- fp32 -> bf16 convert (fallback path only) ----------------
__global__ void k_cvt(const float* __restrict__ src, ushort* __restrict__ dst, int n) {
  int idx = blockIdx.x * blockDim.x + threadIdx.x;
  int stride = gridDim.x * blockDim.x;
  for (int i = idx * 8; i < n; i += stride * 8) {
    float4 a = *(const float4*)(src + i);
    float4 b = *(const float4*)(src + i + 4);
    ushort8v o;
    o[0] = f2bf(a.x); o[1] = f2bf(a.y); o[2] = f2bf(a.z); o[3] = f2bf(a.w);
    o[4] = f2bf(b.x); o[5] = f2bf(b.y); o[6] = f2bf(b.z); o[7] = f2bf(b.w);
    *(ushort8v*)(dst + i) = o;
  }
}

// ------- merged logits (blocks 0..255) + gate|up bf16 build (256..1279) -----
__global__ __launch_bounds__(256) void k_logitsF(
    const float* __restrict__ x, const float* __restrict__ rw,
    const float* __restrict__ aw1, float* __restrict__ partial,
    ushort* __restrict__ Xb,
    const float* __restrict__ g, const float* __restrict__ u,
    ushort* __restrict__ Wgu) {
  const int bid = blockIdx.x;
  const int tid = threadIdx.x;
  if (bid >= 256) {                            // gate|up cvt blocks
    const int cb = bid - 256;
    const int total = NE * NID2 * (HD / 8);
    const int stride = CVTGU * 256;
    for (int i8 = cb * 256 + tid; i8 < total; i8 += stride) {
      const int col = (i8 & (HD / 8 - 1)) * 8;
      const int row = i8 >> 7;
      const int e = row / NID2;
      const int q = row - e * NID2;
      const int p = q >> 7, r = q & 127;
      const float* src = ((r < 64) ? g + ((size_t)e * ID + p * 64 + r) * HD
                                   : u + ((size_t)e * ID + p * 64 + (r - 64)) * HD) + col;
      float4 a = *(const float4*)(src);
      float4 b = *(const float4*)(src + 4);
      ushort8v o;
      o[0] = f2bf(a.x); o[1] = f2bf(a.y); o[2] = f2bf(a.z); o[3] = f2bf(a.w);
      o[4] = f2bf(b.x); o[5] = f2bf(b.y); o[6] = f2bf(b.z); o[7] = f2bf(b.w);
      *(ushort8v*)(Wgu + (size_t)row * HD + col) = o;
    }
    return;
  }
  __shared__ float xs[256][KCH + 1];
  const int c = bid >> 4;
  const int t0 = (bid & 15) * 256;
  const int k0 = c * KCH;
#pragma unroll
  for (int j = 0; j < 16; ++j) {
    const int id4 = j * 256 + tid;
    const int row = id4 >> 4;
    const int c4 = (id4 & 15) * 4;
    float4 v = *(const float4*)(x + (size_t)(t0 + row) * HD + k0 + c4);
    xs[row][c4 + 0] = v.x; xs[row][c4 + 1] = v.y;
    xs[row][c4 + 2] = v.z; xs[row][c4 + 3] = v.w;
    ushort4 o; o.x = f2bf(v.x); o.y = f2bf(v.y); o.z = f2bf(v.z); o.w = f2bf(v.w);
    *(ushort4*)(Xb + (size_t)(t0 + row) * HD + k0 + c4) = o;
  }
  __syncthreads();
  float acc[NROW];
#pragma unroll
  for (int r = 0; r < NROW; ++r) acc[r] = 0.f;
  for (int k4 = 0; k4 < KCH; k4 += 4) {
    const float x0 = xs[tid][k4 + 0], x1 = xs[tid][k4 + 1];
    const float x2 = xs[tid][k4 + 2], x3 = xs[tid][k4 + 3];
#pragma unroll
    for (int r = 0; r < NROW; ++r) {
      const float* wp = ((r < NE) ? (rw + (size_t)r * HD)
                                  : (aw1 + (size_t)(r - NE) * HD)) + k0 + k4;
      acc[r] += x0 * wp[0] + x1 * wp[1] + x2 * wp[2] + x3 * wp[3];
    }
  }
  const int t = t0 + tid;
#pragma unroll
  for (int r = 0; r < NROW; ++r)
    partial[((size_t)c * NROW + r) * TOK + t] = acc[r];
}

// ---------------- fixed-order chunk reduction (r11-proven) ------------------
__global__ __launch_bounds__(256) void k_reduce(
    const float* __restrict__ partial, float* __restrict__ dots) {
  const int t = blockIdx.x * 256 + threadIdx.x;
  const int r = blockIdx.y;
  float s = 0.f;
#pragma unroll
  for (int c = 0; c < NCH; ++c)
    s += partial[((size_t)c * NROW + r) * TOK + t];
  dots[(size_t)r * TOK + t] = s;
}

// ---------------- per-token: softmax, actor, top-k, expert lists ------------
__global__ __launch_bounds__(64) void k_select(
    const float* __restrict__ dots, const float* __restrict__ ab1_,
    const float* __restrict__ aw2_, const float* __restrict__ ab2_,
    float* __restrict__ scores, int* __restrict__ idx, int* __restrict__ cnt) {
  const int lane = threadIdx.x;
  const int t = blockIdx.x * 64 + lane;
  float d[NROW];
#pragma unroll
  for (int r = 0; r < NROW; ++r) d[r] = dots[(size_t)r * TOK + t];
  float m = d[0];
#pragma unroll
  for (int e = 1; e < NE; ++e) m = fmaxf(m, d[e]);
  float p[NE]; float sum = 0.f;
#pragma unroll
  for (int e = 0; e < NE; ++e) { p[e] = expf(d[e] - m); sum += p[e]; }
  float inv = 1.f / sum;
#pragma unroll
  for (int e = 0; e < NE; ++e) p[e] *= inv;
  float lg[MAXK];
#pragma unroll
  for (int k = 0; k < MAXK; ++k) lg[k] = ab2_[k];
#pragma unroll
  for (int i = 0; i < AHID; ++i) {
    float v = d[NE + i] + ab1_[i];
    float gg = 0.5f * v * (1.f + tanhf(0.7978845608028654f * (v + 0.044715f * v * v * v)));
#pragma unroll
    for (int k = 0; k < MAXK; ++k) lg[k] += gg * aw2_[k * AHID + i];
  }
  int best = 0; float bv = fminf(fmaxf(lg[0], -30.f), 30.f);
#pragma unroll
  for (int k = 1; k < MAXK; ++k) {
    float lv = fminf(fmaxf(lg[k], -30.f), 30.f);
    if (lv > bv) { bv = lv; best = k; }
  }
  const int kk = best + 1;
  float sc[NE];
#pragma unroll
  for (int e = 0; e < NE; ++e) {
    int rank = 0;
#pragma unroll
    for (int j = 0; j < NE; ++j)
      rank += (p[j] > p[e]) || (p[j] == p[e] && j < e);
    sc[e] = (rank < kk) ? p[e] : 0.f;
    scores[(size_t)t * NE + e] = sc[e];
  }
#pragma unroll
  for (int e = 0; e < NE; ++e) {
    unsigned long long msk = __ballot(sc[e] > 0.f);
    int npop = __popcll(msk);
    int mypos = __popcll(msk & ((1ull << lane) - 1ull));
    int base = 0;
    if (lane == 0 && npop) base = atomicAdd(cnt + e, npop);
    base = __shfl(base, 0);
    if (sc[e] > 0.f) idx[e * TOK + base + mypos] = t;
  }
}

// ---------------- combined gate|up GEMM + silu exchange (r11-proven) --------
__global__ __launch_bounds__(256, 2) void k_gateupC(
    const ushort* __restrict__ X, const int* __restrict__ idx,
    const int* __restrict__ cnt, const ushort* __restrict__ Wc,
    ushort* __restrict__ act, const int e0, const int actStrideRows,
    const float* __restrict__ dwsrc, ushort* __restrict__ dwdst) {
  __shared__ __attribute__((aligned(16))) ushort lds[BM * BK + BN * BK];  // 32KB
  ushort* As = lds;
  ushort* Bs = lds + BM * BK;

  const int bid = blockIdx.x;
  if (bid >= NB_GUC) {                                  // fused down-w cvt
    if (blockIdx.z != 0) return;
    const int cb = bid - NB_GUC;
    const int ncvt = NE * HD * ID;
    const int stride = CVTB * 256 * 8;
    for (int i = (cb * 256 + (int)threadIdx.x) * 8; i < ncvt; i += stride) {
      float4 a = *(const float4*)(dwsrc + i);
      float4 b = *(const float4*)(dwsrc + i + 4);
      ushort8v o;
      o[0] = f2bf(a.x); o[1] = f2bf(a.y); o[2] = f2bf(a.z); o[3] = f2bf(a.w);
      o[4] = f2bf(b.x); o[5] = f2bf(b.y); o[6] = f2bf(b.z); o[7] = f2bf(b.w);
      *(ushort8v*)(dwdst + i) = o;
    }
    return;
  }

  const int e = e0 + blockIdx.z;
  const int n = cnt[e];
  const int logical = (bid & 7) * (NB_GUC / 8) + (bid >> 3);
  const int tn = logical >> 5;
  const int tm = logical & (NTM - 1);
  const int row0 = tm * BM;
  if (row0 >= n) return;
  const int* idx_e = idx + e * TOK;
  const ushort* WcE = Wc + (size_t)e * NID2 * HD;
  ushort* actE = act + (size_t)actStrideRows * e * ID;

  const int tid = threadIdx.x;
  const int lane = tid & 63;
  const int w = tid >> 6;
  const int wr = (w >> 1) * 64;
  const int wc = (w & 1) * 64;
  const int srow = lane >> 3;
  const int scol = ((lane & 7) ^ srow) * 8;       // T2: inverse-swz source
  const int col0 = tn * BN;

  f32x4 acc[4][4] = {};

  const ushort* pa[4]; const ushort* pb[4];
  ushort* la[4]; ushort* lb[4];
#pragma unroll
  for (int j = 0; j < 4; ++j) {
    const int cc = w * 4 + j;
    const int r = cc * 8 + srow;
    const int token = idx_e[min(row0 + r, n - 1)];
    pa[j] = X   + (size_t)token * HD + scol;
    pb[j] = WcE + (size_t)(col0 + r) * HD + scol;
    la[j] = &As[cc * 512]; lb[j] = &Bs[cc * 512];
  }

  for (int kt = 0; kt < HD / BK; ++kt) {
    const int k0 = kt * BK;
    __syncthreads();
#pragma unroll
    for (int j = 0; j < 4; ++j) {
      GLD_LDS16(pa[j] + k0, la[j]);
      GLD_LDS16(pb[j] + k0, lb[j]);
    }
    __syncthreads();
#pragma unroll
    for (int kk = 0; kk < 2; ++kk) {
      const int kc = kk * 32 + (lane >> 4) * 8;
      const int rr = lane & 15;
      const int kcs = (((kc >> 3) ^ (rr & 7)) << 3);   // T2: swizzled read
      bf16x8 af[4], bf_[4];
#pragma unroll
      for (int m = 0; m < 4; ++m)
        af[m] = *(const bf16x8*)&As[(wr + m * 16 + rr) * BK + kcs];
#pragma unroll
      for (int nn = 0; nn < 4; ++nn)
        bf_[nn] = *(const bf16x8*)&Bs[(wc + nn * 16 + rr) * BK + kcs];
#pragma unroll
      for (int m = 0; m < 4; ++m)
#pragma unroll
        for (int nn = 0; nn < 4; ++nn)
          acc[m][nn] = __builtin_amdgcn_mfma_f32_16x16x32_bf16(af[m], bf_[nn], acc[m][nn], 0, 0, 0);
    }
  }

  const int erow = (lane >> 4) * 4, ecol = lane & 15;
  float* exch = (float*)lds;
  __syncthreads();
  if (w & 1) {                                // u-waves
#pragma unroll
    for (int m = 0; m < 4; ++m) {
      const int rbase = wr + m * 16 + erow;
#pragma unroll
      for (int nn = 0; nn < 4; ++nn) {
        const int c = nn * 16 + ecol;
#pragma unroll
        for (int j = 0; j < 4; ++j)
          exch[(rbase + j) * 64 + c] = acc[m][nn][j];
      }
    }
  }
  __syncthreads();
  if (!(w & 1)) {                             // g-waves
#pragma unroll
    for (int m = 0; m < 4; ++m) {
      const int rbase = wr + m * 16 + erow;
#pragma unroll
      for (int nn = 0; nn < 4; ++nn) {
        const int c = nn * 16 + ecol;
        const int gc = tn * 64 + c;
#pragma unroll
        for (int j = 0; j < 4; ++j) {
          float g = acc[m][nn][j];
          float u = exch[(rbase + j) * 64 + c];
          float h = (g / (1.f + __expf(-g))) * u;
          actE[(size_t)(row0 + rbase + j) * ID + gc] = f2bf(h);
        }
      }
    }
  }
}

// ------- persistent grouped down GEMM (r11 body, grid-stride items) ---------
__global__ __launch_bounds__(256, 2) void k_downP(
    const ushort* __restrict__ act, const ushort* __restrict__ Wd,
    const int* __restrict__ idx, const int* __restrict__ cnt,
    ushort* __restrict__ y) {
  __shared__ __attribute__((aligned(16))) ushort As[BM * BK];
  __shared__ __attribute__((aligned(16))) ushort Bs[BN * BK];

  const int tid = threadIdx.x;
  const int lane = tid & 63;
  const int w = tid >> 6;
  const int wr = (w >> 1) * 64;
  const int wc = (w & 1) * 64;
  const int srow = lane >> 3;
  const int scol = ((lane & 7) ^ srow) * 8;       // T2: inverse-swz source
  const int erow = (lane >> 4) * 4, ecol = lane & 15;

  for (int item = blockIdx.x; item < NE * NB_D; item += PD_BLOCKS) {
    const int e = item >> 8;                      // NB_D = 256
    const int bid = item & (NB_D - 1);
    const int logical = (bid & 7) * (NB_D / 8) + (bid >> 3);
    const int tn = logical >> 5;
    const int tm = logical & (NTM - 1);
    const int n = cnt[e];
    const int row0 = tm * BM;
    if (row0 >= n) continue;
    const int* idx_e = idx + e * TOK;
    const ushort* A = act + (size_t)e * TOK * ID;
    const ushort* W = Wd + (size_t)e * HD * ID;
    ushort* yE = y + (size_t)e * TOK * HD;
    const int col0 = tn * BN;

    f32x4 acc[4][4] = {};

    const ushort* pa[4]; const ushort* pb[4];
    ushort* la[4]; ushort* lb[4];
#pragma unroll
    for (int j = 0; j < 4; ++j) {
      const int cc = w * 4 + j;
      const int r = cc * 8 + srow;
      pa[j] = A + (size_t)min(row0 + r, n - 1) * ID + scol;
      pb[j] = W + (size_t)(col0 + r) * ID + scol;
      la[j] = &As[cc * 512]; lb[j] = &Bs[cc * 512];
    }

    for (int kt = 0; kt < ID / BK; ++kt) {
      const int k0 = kt * BK;
      __syncthreads();
#pragma unroll
      for (int j = 0; j < 4; ++j) {
        GLD_LDS16(pa[j] + k0, la[j]);
        GLD_LDS16(pb[j] + k0, lb[j]);
      }
      __syncthreads();
#pragma unroll
      for (int kk = 0; kk < 2; ++kk) {
        const int kc = kk * 32 + (lane >> 4) * 8;
        const int rr = lane & 15;
        const int kcs = (((kc >> 3) ^ (rr & 7)) << 3);
        bf16x8 af[4], bf_[4];
#pragma unroll
        for (int m = 0; m < 4; ++m)
          af[m] = *(const bf16x8*)&As[(wr + m * 16 + rr) * BK + kcs];
#pragma unroll
        for (int nn = 0; nn < 4; ++nn)
          bf_[nn] = *(const bf16x8*)&Bs[(wc + nn * 16 + rr) * BK + kcs];
#pragma unroll
        for (int m = 0; m < 4; ++m)
#pragma unroll
          for (int nn = 0; nn < 4; ++nn)
            acc[m][nn] = __builtin_amdgcn_mfma_f32_16x16x32_bf16(af[m], bf_[nn], acc[m][nn], 0, 0, 0);
      }
    }

#pragma unroll
    for (int m = 0; m < 4; ++m) {
      const int cr0 = row0 + wr + m * 16 + erow;
#pragma unroll
      for (int j = 0; j < 4; ++j) {
        const int cr = cr0 + j;
        if (cr < n) {
          const int token = idx_e[cr];
          ushort* yp = yE + (size_t)token * HD + col0 + wc;
#pragma unroll
          for (int nn = 0; nn < 4; ++nn)
            yp[nn * 16 + ecol] = f2bf(acc[m][nn][j]);
        }
      }
    }
  }
}

// ---------------- combine: out[t] = sum_e score[t][e] * y[e][t] -------------
__global__ __launch_bounds__(256) void k_combine(
    const ushort* __restrict__ y, const float* __restrict__ scores,
    float* __restrict__ out) {
  const int w = threadIdx.x >> 6, lane = threadIdx.x & 63;
  const int t = blockIdx.x * 4 + w;
  const int c0 = lane * 16;
  float acc[16];
#pragma unroll
  for (int i = 0; i < 16; ++i) acc[i] = 0.f;
  const float* sc = scores + (size_t)t * NE;
#pragma unroll
  for (int e = 0; e < NE; ++e) {
    const float s = sc[e];
    if (s > 0.f) {
      const ushort8v* yp = (const ushort8v*)(y + ((size_t)e * TOK + t) * HD + c0);
      ushort8v v0 = yp[0], v1 = yp[1];
#pragma unroll
      for (int i = 0; i < 8; ++i) acc[i] += s * bf2f(v0[i]);
#pragma unroll
      for (int i = 0; i < 8; ++i) acc[8 + i] += s * bf2f(v1[i]);
    }
  }
  float* op = out + (size_t)t * HD + c0;
#pragma unroll
  for (int i = 0; i < 4; ++i)
    *(float4*)(op + 4 * i) = make_float4(acc[4*i], acc[4*i+1], acc[4*i+2], acc[4*i+3]);
}

// ---------------- fallback down (per-expert, accumulate into out) -----------
__global__ __launch_bounds__(256) void k_down64(
    const ushort* __restrict__ act, const ushort* __restrict__ Wd,
    const float* __restrict__ scores, const int* __restrict__ idx,
    const int* __restrict__ cnt, const int e, float* __restrict__ out) {
  __shared__ __attribute__((aligned(16))) ushort As[64 * 64];
  __shared__ __attribute__((aligned(16))) ushort Bs[64 * 64];
  const int n = cnt[e];
  const int row0 = blockIdx.y * 64;
  if (row0 >= n) return;
  const int* idx_e = idx + e * TOK;
  const ushort* A = act;
  const ushort* W = Wd + (size_t)e * HD * ID;
  const int col0 = blockIdx.x * 64;
  const int tid = threadIdx.x, lane = tid & 63, w = tid >> 6;
  const int wr = (w >> 1) * 32, wc = (w & 1) * 32;
  const int srow = lane >> 3, scol = (lane & 7) * 8;
  f32x4 acc[2][2] = {};
  const ushort* pa[2]; const ushort* pb[2];
  ushort* la[2]; ushort* lb[2];
#pragma unroll
  for (int j = 0; j < 2; ++j) {
    const int cc = w * 2 + j;
    const int r = cc * 8 + srow;
    pa[j] = A + (size_t)min(row0 + r, n - 1) * ID + scol;
    pb[j] = W + (size_t)(col0 + r) * ID + scol;
    la[j] = &As[cc * 512]; lb[j] = &Bs[cc * 512];
  }
  for (int kt = 0; kt < ID / 64; ++kt) {
    const int k0 = kt * 64;
    __syncthreads();
#pragma unroll
    for (int j = 0; j < 2; ++j) { GLD_LDS16(pa[j] + k0, la[j]); GLD_LDS16(pb[j] + k0, lb[j]); }
    __syncthreads();
#pragma unroll
    for (int kk = 0; kk < 2; ++kk) {
      const int kc = kk * 32 + (lane >> 4) * 8;
      const int rr = lane & 15;
      bf16x8 af[2], bf_[2];
#pragma unroll
      for (int m = 0; m < 2; ++m) af[m] = *(const bf16x8*)&As[(wr + m * 16 + rr) * 64 + kc];
#pragma unroll
      for (int nn = 0; nn < 2; ++nn) bf_[nn] = *(const bf16x8*)&Bs[(wc + nn * 16 + rr) * 64 + kc];
#pragma unroll
      for (int m = 0; m < 2; ++m)
#pragma unroll
        for (int nn = 0; nn < 2; ++nn)
          acc[m][nn] = __builtin_amdgcn_mfma_f32_16x16x32_bf16(af[m], bf_[nn], acc[m][nn], 0, 0, 0);
    }
  }
  const int erow = (lane >> 4) * 4, ecol = lane & 15;
#pragma unroll
  for (int m = 0; m < 2; ++m) {
    const int cr0 = row0 + wr + m * 16 + erow;
#pragma unroll
    for (int j = 0; j < 4; ++j) {
      const int cr = cr0 + j;
      if (cr < n) {
        const int token = idx_e[cr];
        const float s = scores[(size_t)token * NE + e];
        float* op = out + (size_t)token * HD + col0 + wc;
#pragma unroll
        for (int nn = 0; nn < 2; ++nn) op[nn * 16 + ecol] += s * acc[m][nn][j];
      }
    }
  }
}

extern "C" void kernel_launch(void* const* d_in, const int* in_sizes, int n_in,
                              void* d_out, int out_size, void* d_ws, size_t ws_size,
                              hipStream_t stream) {
  const float* hs       = (const float*)d_in[0];
  const float* router_w = (const float*)d_in[1];
  const float* actor_w1 = (const float*)d_in[2];
  const float* actor_b1 = (const float*)d_in[3];
  const float* actor_w2 = (const float*)d_in[4];
  const float* actor_b2 = (const float*)d_in[5];
  const float* gate_w   = (const float*)d_in[6];
  const float* up_w     = (const float*)d_in[7];
  const float* down_w   = (const float*)d_in[8];
  float* out = (float*)d_out;

  const size_t sz_x    = (size_t)TOK * HD * 2;              // 8 MB
  const size_t sz_w    = (size_t)NE * ID * HD * 2;          // 44 MB
  const size_t sz_wgu  = 2 * sz_w;                          // 88 MB combined
  const size_t sz_act1 = (size_t)TOK * ID * 2;              // 22 MB (fallback)
  const size_t sz_actC = (size_t)NE * TOK * ID * 2;         // 176 MB
  const size_t sz_part = (size_t)NCH * NROW * TOK * 4;      // 15.2 MB (aliases act)
  const size_t sz_dt   = (size_t)NROW * TOK * 4;
  const size_t sz_sc   = (size_t)TOK * NE * 4;
  const size_t sz_ix   = (size_t)NE * TOK * 4;

  const size_t fixed = sz_x + sz_wgu + sz_w;                // 140 MB
  const size_t tail  = sz_dt + sz_sc + sz_ix + 256;
  const size_t fb_act = (sz_act1 > sz_part ? sz_act1 : sz_part);
  const size_t need_fb = fixed + fb_act + tail;
  const size_t need_cb = fixed + sz_actC + tail;
  if (ws_size < need_fb) return;
  const bool combined = (ws_size >= need_cb);
  const size_t act_sz = combined ? sz_actC : fb_act;

  char* ws = (char*)d_ws;
  ushort* Xb  = (ushort*)ws;
  ushort* Wgu = (ushort*)(ws + sz_x);
  ushort* Wdb = (ushort*)(ws + sz_x + sz_wgu);
  ushort* yb  = Wgu;                                        // alias (Wgu dead after gateup)
  ushort* act = (ushort*)(ws + fixed);
  float*  partial = (float*)(ws + fixed);                   // aliases act
  float*  dots   = (float*)(ws + fixed + act_sz);
  float*  scores = (float*)(ws + fixed + act_sz + sz_dt);
  int*    idx    = (int*)  (ws + fixed + act_sz + sz_dt + sz_sc);
  int*    cnt    = (int*)  (ws + fixed + act_sz + sz_dt + sz_sc + sz_ix);

  hipMemsetAsync(cnt, 0, NE * 4, stream);

  // logits + gate|up cvt in one dispatch (independent work packed together)
  k_logitsF<<<256 + CVTGU, 256, 0, stream>>>(hs, router_w, actor_w1, partial, Xb,
                                             gate_w, up_w, Wgu);
  k_reduce<<<dim3(TOK / 256, NROW), 256, 0, stream>>>(partial, dots);
  k_select<<<TOK / 64, 64, 0, stream>>>(dots, actor_b1, actor_w2, actor_b2,
                                        scores, idx, cnt);

  if (combined) {
    k_gateupC<<<dim3(NB_GUC + CVTB, 1, NE), 256, 0, stream>>>(
        Xb, idx, cnt, Wgu, act, 0, TOK, down_w, Wdb);
    k_downP<<<PD_BLOCKS, 256, 0, stream>>>(act, Wdb, idx, cnt, yb);
    k_combine<<<TOK / 4, 256, 0, stream>>>(yb, scores, out);
  } else {
    hipMemsetAsync(out, 0, (size_t)TOK * HD * 4, stream);
    k_cvt<<<2048, 256, 0, stream>>>(down_w, Wdb, NE * ID * HD);
    for (int e = 0; e < NE; ++e) {
      k_gateupC<<<dim3(NB_GUC, 1, 1), 256, 0, stream>>>(
          Xb, idx, cnt, Wgu, act, e, 0, nullptr, nullptr);
      k_down64<<<dim3(HD / 64, TOK / 64), 256, 0, stream>>>(
          act, Wdb, scores, idx, cnt, e, out);
    }
  }
}

// Round 16
// 469.825 us; speedup vs baseline: 1.5297x; 1.0470x over previous
//
#include <hip/hip_runtime.h>
#include <hip/hip_bf16.h>
#include <stdint.h>

#define TOK 4096   // B*S
#define HD  1024   // H
#define NE  8      // experts
#define ID  2688   // I
#define MAXK 6
#define AHID 50
#define NROW 58    // NE + AHID
#define KCH 64     // logits split-K chunk
#define NCH (HD / KCH)  // 16

#define BM 128
#define BN 128
#define BK 64
#define NTM (TOK / BM)          // 32
#define NID2 (2 * ID)           // 5376 combined gate|up cols
#define NTN_GUC (NID2 / BN)     // 42
#define NB_GUC (NTN_GUC * NTM)  // 1344 (divisible by 8 -> bijective swizzle)
#define NTN_D (HD / BN)         // 8
#define NB_D (NTN_D * NTM)      // 256
#define CVTB 384                // fused down-w cvt blocks (z=0 only)

typedef float  f32x4  __attribute__((ext_vector_type(4)));
typedef __bf16 bf16x8 __attribute__((ext_vector_type(8)));
typedef ushort ushort8v __attribute__((ext_vector_type(8)));

__device__ __forceinline__ ushort f2bf(float f) {
  union { float f; uint32_t u; } v; v.f = f;
  return (ushort)((v.u + 0x7FFFu + ((v.u >> 16) & 1u)) >> 16);  // RNE
}
__device__ __forceinline__ float bf2f(ushort u) {
  union { uint32_t u; float f; } v; v.u = (uint32_t)u << 16; return v.f;
}

// global -> LDS direct load, 16B per lane. LDS dest must be wave-uniform.
#define GLD_LDS16(gp, lp)                                                      \
  __builtin_amdgcn_global_load_lds(                                            \
      (const __attribute__((address_space(1))) uint32_t*)(uintptr_t)(gp),      \
      (__attribute__((address_space(3))) uint32_t*)(uint32_t)(uintptr_t)(lp),  \
      16, 0, 0)

// ---------------- fp32 -> bf16 convert (fallback path only) ----------------
__global__ void k_cvt(const float* __restrict__ src, ushort* __restrict__ dst, int n) {
  int idx = blockIdx.x * blockDim.x + threadIdx.x;
  int stride = gridDim.x * blockDim.x;
  for (int i = idx * 8; i < n; i += stride * 8) {
    float4 a = *(const float4*)(src + i);
    float4 b = *(const float4*)(src + i + 4);
    ushort8v o;
    o[0] = f2bf(a.x); o[1] = f2bf(a.y); o[2] = f2bf(a.z); o[3] = f2bf(a.w);
    o[4] = f2bf(b.x); o[5] = f2bf(b.y); o[6] = f2bf(b.z); o[7] = f2bf(b.w);
    *(ushort8v*)(dst + i) = o;
  }
}

// ---------------- fp32 -> bf16 combined gate|up interleaved build -----------
// dst[e][q][h], q = p*128 + r; r<64 -> gate row p*64+r; r>=64 -> up row p*64+r-64
__global__ void k_cvt_gu(const float* __restrict__ g, const float* __restrict__ u,
                         ushort* __restrict__ dst) {
  const int total = NE * NID2 * (HD / 8);
  int idx = blockIdx.x * blockDim.x + threadIdx.x;
  int stride = gridDim.x * blockDim.x;
  for (int i8 = idx; i8 < total; i8 += stride) {
    const int col = (i8 & (HD / 8 - 1)) * 8;
    const int row = i8 >> 7;
    const int e = row / NID2;
    const int q = row - e * NID2;
    const int p = q >> 7, r = q & 127;
    const float* src = ((r < 64) ? g + ((size_t)e * ID + p * 64 + r) * HD
                                 : u + ((size_t)e * ID + p * 64 + (r - 64)) * HD) + col;
    float4 a = *(const float4*)(src);
    float4 b = *(const float4*)(src + 4);
    ushort8v o;
    o[0] = f2bf(a.x); o[1] = f2bf(a.y); o[2] = f2bf(a.z); o[3] = f2bf(a.w);
    o[4] = f2bf(b.x); o[5] = f2bf(b.y); o[6] = f2bf(b.z); o[7] = f2bf(b.w);
    *(ushort8v*)(dst + (size_t)row * HD + col) = o;
  }
}

// ---------------- logits split-K: LDS-staged x, SGPR W; emits bf16 Xb -------
__global__ __launch_bounds__(256) void k_logits(
    const float* __restrict__ x, const float* __restrict__ rw,
    const float* __restrict__ aw1, float* __restrict__ partial,
    ushort* __restrict__ Xb) {
  __shared__ float xs[256][KCH + 1];
  const int tid = threadIdx.x;
  const int t0 = blockIdx.x * 256;
  const int c = blockIdx.y;
  const int k0 = c * KCH;
#pragma unroll
  for (int j = 0; j < 16; ++j) {
    const int id4 = j * 256 + tid;
    const int row = id4 >> 4;
    const int c4 = (id4 & 15) * 4;
    float4 v = *(const float4*)(x + (size_t)(t0 + row) * HD + k0 + c4);
    xs[row][c4 + 0] = v.x; xs[row][c4 + 1] = v.y;
    xs[row][c4 + 2] = v.z; xs[row][c4 + 3] = v.w;
    ushort4 o; o.x = f2bf(v.x); o.y = f2bf(v.y); o.z = f2bf(v.z); o.w = f2bf(v.w);
    *(ushort4*)(Xb + (size_t)(t0 + row) * HD + k0 + c4) = o;
  }
  __syncthreads();
  float acc[NROW];
#pragma unroll
  for (int r = 0; r < NROW; ++r) acc[r] = 0.f;
  for (int k4 = 0; k4 < KCH; k4 += 4) {
    const float x0 = xs[tid][k4 + 0], x1 = xs[tid][k4 + 1];
    const float x2 = xs[tid][k4 + 2], x3 = xs[tid][k4 + 3];
#pragma unroll
    for (int r = 0; r < NROW; ++r) {
      const float* wp = ((r < NE) ? (rw + (size_t)r * HD)
                                  : (aw1 + (size_t)(r - NE) * HD)) + k0 + k4;
      acc[r] += x0 * wp[0] + x1 * wp[1] + x2 * wp[2] + x3 * wp[3];
    }
  }
  const int t = t0 + tid;
#pragma unroll
  for (int r = 0; r < NROW; ++r)
    partial[((size_t)c * NROW + r) * TOK + t] = acc[r];
}

// ---------------- fixed-order chunk reduction -------------------------------
__global__ __launch_bounds__(256) void k_reduce(
    const float* __restrict__ partial, float* __restrict__ dots) {
  const int t = blockIdx.x * 256 + threadIdx.x;
  const int r = blockIdx.y;
  float s = 0.f;
#pragma unroll
  for (int c = 0; c < NCH; ++c)
    s += partial[((size_t)c * NROW + r) * TOK + t];
  dots[(size_t)r * TOK + t] = s;
}

// ---------------- per-token: softmax, actor, top-k, expert lists ------------
__global__ __launch_bounds__(64) void k_select(
    const float* __restrict__ dots, const float* __restrict__ ab1_,
    const float* __restrict__ aw2_, const float* __restrict__ ab2_,
    float* __restrict__ scores, int* __restrict__ idx, int* __restrict__ cnt) {
  const int lane = threadIdx.x;
  const int t = blockIdx.x * 64 + lane;
  float d[NROW];
#pragma unroll
  for (int r = 0; r < NROW; ++r) d[r] = dots[(size_t)r * TOK + t];
  float m = d[0];
#pragma unroll
  for (int e = 1; e < NE; ++e) m = fmaxf(m, d[e]);
  float p[NE]; float sum = 0.f;
#pragma unroll
  for (int e = 0; e < NE; ++e) { p[e] = expf(d[e] - m); sum += p[e]; }
  float inv = 1.f / sum;
#pragma unroll
  for (int e = 0; e < NE; ++e) p[e] *= inv;
  float lg[MAXK];
#pragma unroll
  for (int k = 0; k < MAXK; ++k) lg[k] = ab2_[k];
#pragma unroll
  for (int i = 0; i < AHID; ++i) {
    float v = d[NE + i] + ab1_[i];
    float gg = 0.5f * v * (1.f + tanhf(0.7978845608028654f * (v + 0.044715f * v * v * v)));
#pragma unroll
    for (int k = 0; k < MAXK; ++k) lg[k] += gg * aw2_[k * AHID + i];
  }
  int best = 0; float bv = fminf(fmaxf(lg[0], -30.f), 30.f);
#pragma unroll
  for (int k = 1; k < MAXK; ++k) {
    float lv = fminf(fmaxf(lg[k], -30.f), 30.f);
    if (lv > bv) { bv = lv; best = k; }
  }
  const int kk = best + 1;
  float sc[NE];
#pragma unroll
  for (int e = 0; e < NE; ++e) {
    int rank = 0;
#pragma unroll
    for (int j = 0; j < NE; ++j)
      rank += (p[j] > p[e]) || (p[j] == p[e] && j < e);
    sc[e] = (rank < kk) ? p[e] : 0.f;
    scores[(size_t)t * NE + e] = sc[e];
  }
#pragma unroll
  for (int e = 0; e < NE; ++e) {
    unsigned long long msk = __ballot(sc[e] > 0.f);
    int npop = __popcll(msk);
    int mypos = __popcll(msk & ((1ull << lane) - 1ull));
    int base = 0;
    if (lane == 0 && npop) base = atomicAdd(cnt + e, npop);
    base = __shfl(base, 0);
    if (sc[e] > 0.f) idx[e * TOK + base + mypos] = t;
  }
}

// ---------------- combined gate|up GEMM, in-register silu epilogue ----------
// Panel tn: B-rows 0..63 = gate cols [tn*64,+64), rows 64..127 = up same cols.
// NEW fragment mapping: wave reads B rows {wq*32, wq*32+16, 64+wq*32, 80+wq*32}
// (wq = w&1) so acc[m][0..1] = gate and acc[m][2..3] = up for the SAME output
// columns -> h = silu(acc[m][n]) * acc[m][n+2] computed in-register, no LDS
// exchange, no extra barriers; all 4 waves store a 64-row x 32-col slice.
__global__ __launch_bounds__(256, 2) void k_gateupC(
    const ushort* __restrict__ X, const int* __restrict__ idx,
    const int* __restrict__ cnt, const ushort* __restrict__ Wc,
    ushort* __restrict__ act, const int e0, const int actStrideRows,
    const float* __restrict__ dwsrc, ushort* __restrict__ dwdst) {
  __shared__ __attribute__((aligned(16))) ushort lds[BM * BK + BN * BK];  // 32KB
  ushort* As = lds;
  ushort* Bs = lds + BM * BK;

  const int bid = blockIdx.x;
  if (bid >= NB_GUC) {                                  // fused down-w cvt
    if (blockIdx.z != 0) return;
    const int cb = bid - NB_GUC;
    const int ncvt = NE * HD * ID;
    const int stride = CVTB * 256 * 8;
    for (int i = (cb * 256 + (int)threadIdx.x) * 8; i < ncvt; i += stride) {
      float4 a = *(const float4*)(dwsrc + i);
      float4 b = *(const float4*)(dwsrc + i + 4);
      ushort8v o;
      o[0] = f2bf(a.x); o[1] = f2bf(a.y); o[2] = f2bf(a.z); o[3] = f2bf(a.w);
      o[4] = f2bf(b.x); o[5] = f2bf(b.y); o[6] = f2bf(b.z); o[7] = f2bf(b.w);
      *(ushort8v*)(dwdst + i) = o;
    }
    return;
  }

  const int e = e0 + blockIdx.z;
  const int n = cnt[e];
  const int logical = (bid & 7) * (NB_GUC / 8) + (bid >> 3);
  const int tn = logical >> 5;                          // 0..41
  const int tm = logical & (NTM - 1);
  const int row0 = tm * BM;
  if (row0 >= n) return;
  const int* idx_e = idx + e * TOK;
  const ushort* WcE = Wc + (size_t)e * NID2 * HD;
  ushort* actE = act + (size_t)actStrideRows * e * ID;

  const int tid = threadIdx.x;
  const int lane = tid & 63;
  const int w = tid >> 6;
  const int wr = (w >> 1) * 64;                   // M half
  const int wq = w & 1;                           // col half (32-wide)
  const int srow = lane >> 3;
  const int scol = ((lane & 7) ^ srow) * 8;       // T2: inverse-swz source
  const int col0 = tn * BN;

  f32x4 acc[4][4] = {};

  const ushort* pa[4]; const ushort* pb[4];
  ushort* la[4]; ushort* lb[4];
#pragma unroll
  for (int j = 0; j < 4; ++j) {
    const int cc = w * 4 + j;
    const int r = cc * 8 + srow;
    const int token = idx_e[min(row0 + r, n - 1)];
    pa[j] = X   + (size_t)token * HD + scol;
    pb[j] = WcE + (size_t)(col0 + r) * HD + scol;
    la[j] = &As[cc * 512]; lb[j] = &Bs[cc * 512];
  }

  // B fragment panel-row bases: gate (rows wq*32, wq*32+16) then up (+64)
  const int bR0 = wq * 32, bR1 = wq * 32 + 16;
  const int bR2 = 64 + wq * 32, bR3 = 80 + wq * 32;

  for (int kt = 0; kt < HD / BK; ++kt) {
    const int k0 = kt * BK;
    __syncthreads();
#pragma unroll
    for (int j = 0; j < 4; ++j) {
      GLD_LDS16(pa[j] + k0, la[j]);
      GLD_LDS16(pb[j] + k0, lb[j]);
    }
    __syncthreads();
#pragma unroll
    for (int kk = 0; kk < 2; ++kk) {
      const int kc = kk * 32 + (lane >> 4) * 8;
      const int rr = lane & 15;
      const int kcs = (((kc >> 3) ^ (rr & 7)) << 3);   // T2: swizzled read
      bf16x8 af[4], bf_[4];
#pragma unroll
      for (int m = 0; m < 4; ++m)
        af[m] = *(const bf16x8*)&As[(wr + m * 16 + rr) * BK + kcs];
      bf_[0] = *(const bf16x8*)&Bs[(bR0 + rr) * BK + kcs];
      bf_[1] = *(const bf16x8*)&Bs[(bR1 + rr) * BK + kcs];
      bf_[2] = *(const bf16x8*)&Bs[(bR2 + rr) * BK + kcs];
      bf_[3] = *(const bf16x8*)&Bs[(bR3 + rr) * BK + kcs];
#pragma unroll
      for (int m = 0; m < 4; ++m)
#pragma unroll
        for (int nn = 0; nn < 4; ++nn)
          acc[m][nn] = __builtin_amdgcn_mfma_f32_16x16x32_bf16(af[m], bf_[nn], acc[m][nn], 0, 0, 0);
    }
  }

  // ---- in-register silu epilogue: acc[m][n] = gate, acc[m][n+2] = up ----
  const int erow = (lane >> 4) * 4, ecol = lane & 15;
#pragma unroll
  for (int m = 0; m < 4; ++m) {
    const int gr = row0 + wr + m * 16 + erow;
#pragma unroll
    for (int nn = 0; nn < 2; ++nn) {
      const int gc = tn * 64 + wq * 32 + nn * 16 + ecol;
#pragma unroll
      for (int j = 0; j < 4; ++j) {
        float g = acc[m][nn][j];
        float u = acc[m][nn + 2][j];
        float h = (g / (1.f + __expf(-g))) * u;
        actE[(size_t)(gr + j) * ID + gc] = f2bf(h);
      }
    }
  }
}

// ---------------- grouped down GEMM (128x128) -> y[e][token] (bf16) ---------
__global__ __launch_bounds__(256, 2) void k_down(
    const ushort* __restrict__ act, const ushort* __restrict__ Wd,
    const int* __restrict__ idx, const int* __restrict__ cnt,
    ushort* __restrict__ y) {
  __shared__ __attribute__((aligned(16))) ushort As[BM * BK];
  __shared__ __attribute__((aligned(16))) ushort Bs[BN * BK];

  const int e = blockIdx.z;
  const int n = cnt[e];
  const int bid = blockIdx.x;                       // 0..255
  const int logical = (bid & 7) * (NB_D / 8) + (bid >> 3);
  const int tn = logical >> 5;
  const int tm = logical & (NTM - 1);
  const int row0 = tm * BM;
  if (row0 >= n) return;
  const int* idx_e = idx + e * TOK;
  const ushort* A = act + (size_t)e * TOK * ID;
  const ushort* W = Wd + (size_t)e * HD * ID;
  ushort* yE = y + (size_t)e * TOK * HD;

  const int tid = threadIdx.x;
  const int lane = tid & 63;
  const int w = tid >> 6;
  const int wr = (w >> 1) * 64;
  const int wc = (w & 1) * 64;
  const int srow = lane >> 3;
  const int scol = ((lane & 7) ^ srow) * 8;       // T2: inverse-swz source
  const int col0 = tn * BN;

  f32x4 acc[4][4] = {};

  const ushort* pa[4]; const ushort* pb[4];
  ushort* la[4]; ushort* lb[4];
#pragma unroll
  for (int j = 0; j < 4; ++j) {
    const int cc = w * 4 + j;
    const int r = cc * 8 + srow;
    pa[j] = A + (size_t)min(row0 + r, n - 1) * ID + scol;
    pb[j] = W + (size_t)(col0 + r) * ID + scol;
    la[j] = &As[cc * 512]; lb[j] = &Bs[cc * 512];
  }

  for (int kt = 0; kt < ID / BK; ++kt) {
    const int k0 = kt * BK;
    __syncthreads();
#pragma unroll
    for (int j = 0; j < 4; ++j) {
      GLD_LDS16(pa[j] + k0, la[j]);
      GLD_LDS16(pb[j] + k0, lb[j]);
    }
    __syncthreads();
#pragma unroll
    for (int kk = 0; kk < 2; ++kk) {
      const int kc = kk * 32 + (lane >> 4) * 8;
      const int rr = lane & 15;
      const int kcs = (((kc >> 3) ^ (rr & 7)) << 3);   // T2: swizzled read
      bf16x8 af[4], bf_[4];
#pragma unroll
      for (int m = 0; m < 4; ++m)
        af[m] = *(const bf16x8*)&As[(wr + m * 16 + rr) * BK + kcs];
#pragma unroll
      for (int nn = 0; nn < 4; ++nn)
        bf_[nn] = *(const bf16x8*)&Bs[(wc + nn * 16 + rr) * BK + kcs];
#pragma unroll
      for (int m = 0; m < 4; ++m)
#pragma unroll
        for (int nn = 0; nn < 4; ++nn)
          acc[m][nn] = __builtin_amdgcn_mfma_f32_16x16x32_bf16(af[m], bf_[nn], acc[m][nn], 0, 0, 0);
    }
  }

  const int erow = (lane >> 4) * 4, ecol = lane & 15;
#pragma unroll
  for (int m = 0; m < 4; ++m) {
    const int cr0 = row0 + wr + m * 16 + erow;
#pragma unroll
    for (int j = 0; j < 4; ++j) {
      const int cr = cr0 + j;
      if (cr < n) {
        const int token = idx_e[cr];
        ushort* yp = yE + (size_t)token * HD + col0 + wc;
#pragma unroll
        for (int nn = 0; nn < 4; ++nn)
          yp[nn * 16 + ecol] = f2bf(acc[m][nn][j]);
      }
    }
  }
}

// ---------------- combine: out[t] = sum_e score[t][e] * y[e][t] -------------
__global__ __launch_bounds__(256) void k_combine(
    const ushort* __restrict__ y, const float* __restrict__ scores,
    float* __restrict__ out) {
  const int w = threadIdx.x >> 6, lane = threadIdx.x & 63;
  const int t = blockIdx.x * 4 + w;
  const int c0 = lane * 16;
  float acc[16];
#pragma unroll
  for (int i = 0; i < 16; ++i) acc[i] = 0.f;
  const float* sc = scores + (size_t)t * NE;
#pragma unroll
  for (int e = 0; e < NE; ++e) {
    const float s = sc[e];
    if (s > 0.f) {
      const ushort8v* yp = (const ushort8v*)(y + ((size_t)e * TOK + t) * HD + c0);
      ushort8v v0 = yp[0], v1 = yp[1];
#pragma unroll
      for (int i = 0; i < 8; ++i) acc[i] += s * bf2f(v0[i]);
#pragma unroll
      for (int i = 0; i < 8; ++i) acc[8 + i] += s * bf2f(v1[i]);
    }
  }
  float* op = out + (size_t)t * HD + c0;
#pragma unroll
  for (int i = 0; i < 4; ++i)
    *(float4*)(op + 4 * i) = make_float4(acc[4*i], acc[4*i+1], acc[4*i+2], acc[4*i+3]);
}

// ---------------- fallback down (per-expert, accumulate into out) -----------
__global__ __launch_bounds__(256) void k_down64(
    const ushort* __restrict__ act, const ushort* __restrict__ Wd,
    const float* __restrict__ scores, const int* __restrict__ idx,
    const int* __restrict__ cnt, const int e, float* __restrict__ out) {
  __shared__ __attribute__((aligned(16))) ushort As[64 * 64];
  __shared__ __attribute__((aligned(16))) ushort Bs[64 * 64];
  const int n = cnt[e];
  const int row0 = blockIdx.y * 64;
  if (row0 >= n) return;
  const int* idx_e = idx + e * TOK;
  const ushort* A = act;
  const ushort* W = Wd + (size_t)e * HD * ID;
  const int col0 = blockIdx.x * 64;
  const int tid = threadIdx.x, lane = tid & 63, w = tid >> 6;
  const int wr = (w >> 1) * 32, wc = (w & 1) * 32;
  const int srow = lane >> 3, scol = (lane & 7) * 8;
  f32x4 acc[2][2] = {};
  const ushort* pa[2]; const ushort* pb[2];
  ushort* la[2]; ushort* lb[2];
#pragma unroll
  for (int j = 0; j < 2; ++j) {
    const int cc = w * 2 + j;
    const int r = cc * 8 + srow;
    pa[j] = A + (size_t)min(row0 + r, n - 1) * ID + scol;
    pb[j] = W + (size_t)(col0 + r) * ID + scol;
    la[j] = &As[cc * 512]; lb[j] = &Bs[cc * 512];
  }
  for (int kt = 0; kt < ID / 64; ++kt) {
    const int k0 = kt * 64;
    __syncthreads();
#pragma unroll
    for (int j = 0; j < 2; ++j) { GLD_LDS16(pa[j] + k0, la[j]); GLD_LDS16(pb[j] + k0, lb[j]); }
    __syncthreads();
#pragma unroll
    for (int kk = 0; kk < 2; ++kk) {
      const int kc = kk * 32 + (lane >> 4) * 8;
      const int rr = lane & 15;
      bf16x8 af[2], bf_[2];
#pragma unroll
      for (int m = 0; m < 2; ++m) af[m] = *(const bf16x8*)&As[(wr + m * 16 + rr) * 64 + kc];
#pragma unroll
      for (int nn = 0; nn < 2; ++nn) bf_[nn] = *(const bf16x8*)&Bs[(wc + nn * 16 + rr) * 64 + kc];
#pragma unroll
      for (int m = 0; m < 2; ++m)
#pragma unroll
        for (int nn = 0; nn < 2; ++nn)
          acc[m][nn] = __builtin_amdgcn_mfma_f32_16x16x32_bf16(af[m], bf_[nn], acc[m][nn], 0, 0, 0);
    }
  }
  const int erow = (lane >> 4) * 4, ecol = lane & 15;
#pragma unroll
  for (int m = 0; m < 2; ++m) {
    const int cr0 = row0 + wr + m * 16 + erow;
#pragma unroll
    for (int j = 0; j < 4; ++j) {
      const int cr = cr0 + j;
      if (cr < n) {
        const int token = idx_e[cr];
        const float s = scores[(size_t)token * NE + e];
        float* op = out + (size_t)token * HD + col0 + wc;
#pragma unroll
        for (int nn = 0; nn < 2; ++nn) op[nn * 16 + ecol] += s * acc[m][nn][j];
      }
    }
  }
}

extern "C" void kernel_launch(void* const* d_in, const int* in_sizes, int n_in,
                              void* d_out, int out_size, void* d_ws, size_t ws_size,
                              hipStream_t stream) {
  const float* hs       = (const float*)d_in[0];
  const float* router_w = (const float*)d_in[1];
  const float* actor_w1 = (const float*)d_in[2];
  const float* actor_b1 = (const float*)d_in[3];
  const float* actor_w2 = (const float*)d_in[4];
  const float* actor_b2 = (const float*)d_in[5];
  const float* gate_w   = (const float*)d_in[6];
  const float* up_w     = (const float*)d_in[7];
  const float* down_w   = (const float*)d_in[8];
  float* out = (float*)d_out;

  const size_t sz_x    = (size_t)TOK * HD * 2;              // 8 MB
  const size_t sz_w    = (size_t)NE * ID * HD * 2;          // 44 MB
  const size_t sz_wgu  = 2 * sz_w;                          // 88 MB combined
  const size_t sz_act1 = (size_t)TOK * ID * 2;              // 22 MB (fallback)
  const size_t sz_actC = (size_t)NE * TOK * ID * 2;         // 176 MB
  const size_t sz_part = (size_t)NCH * NROW * TOK * 4;      // 15.2 MB (aliases act)
  const size_t sz_dt   = (size_t)NROW * TOK * 4;
  const size_t sz_sc   = (size_t)TOK * NE * 4;
  const size_t sz_ix   = (size_t)NE * TOK * 4;

  const size_t fixed = sz_x + sz_wgu + sz_w;                // 140 MB
  const size_t tail  = sz_dt + sz_sc + sz_ix + 256;
  const size_t fb_act = (sz_act1 > sz_part ? sz_act1 : sz_part);
  const size_t need_fb = fixed + fb_act + tail;
  // y (64 MB) aliases Wgu (88 MB): Wgu dead after k_gateupC; y written by
  // k_down, consumed by k_combine, rebuilt by next call's k_cvt_gu.
  const size_t need_cb = fixed + sz_actC + tail;
  if (ws_size < need_fb) return;
  const bool combined = (ws_size >= need_cb);
  const size_t act_sz = combined ? sz_actC : fb_act;

  char* ws = (char*)d_ws;
  ushort* Xb  = (ushort*)ws;
  ushort* Wgu = (ushort*)(ws + sz_x);
  ushort* Wdb = (ushort*)(ws + sz_x + sz_wgu);
  ushort* yb  = Wgu;                                        // alias (see above)
  ushort* act = (ushort*)(ws + fixed);
  float*  partial = (float*)(ws + fixed);                   // aliases act
  float*  dots   = (float*)(ws + fixed + act_sz);
  float*  scores = (float*)(ws + fixed + act_sz + sz_dt);
  int*    idx    = (int*)  (ws + fixed + act_sz + sz_dt + sz_sc);
  int*    cnt    = (int*)  (ws + fixed + act_sz + sz_dt + sz_sc + sz_ix);

  hipMemsetAsync(cnt, 0, NE * 4, stream);

  k_cvt_gu<<<2048, 256, 0, stream>>>(gate_w, up_w, Wgu);

  k_logits<<<dim3(TOK / 256, NCH), 256, 0, stream>>>(hs, router_w, actor_w1, partial, Xb);
  k_reduce<<<dim3(TOK / 256, NROW), 256, 0, stream>>>(partial, dots);
  k_select<<<TOK / 64, 64, 0, stream>>>(dots, actor_b1, actor_w2, actor_b2,
                                        scores, idx, cnt);

  if (combined) {
    // down-w cvt fused into gateupC's grid (extra x-blocks, z=0 only)
    k_gateupC<<<dim3(NB_GUC + CVTB, 1, NE), 256, 0, stream>>>(
        Xb, idx, cnt, Wgu, act, 0, TOK, down_w, Wdb);
    k_down<<<dim3(NB_D, 1, NE), 256, 0, stream>>>(act, Wdb, idx, cnt, yb);
    k_combine<<<TOK / 4, 256, 0, stream>>>(yb, scores, out);
  } else {
    hipMemsetAsync(out, 0, (size_t)TOK * HD * 4, stream);
    k_cvt<<<2048, 256, 0, stream>>>(down_w, Wdb, NE * ID * HD);
    for (int e = 0; e < NE; ++e) {
      k_gateupC<<<dim3(NB_GUC, 1, 1), 256, 0, stream>>>(
          Xb, idx, cnt, Wgu, act, e, 0, nullptr, nullptr);
      k_down64<<<dim3(HD / 64, TOK / 64), 256, 0, stream>>>(
          act, Wdb, scores, idx, cnt, e, out);
    }
  }
}